// Round 1
// baseline (188.527 us; speedup 1.0000x reference)
//
#include <hip/hip_runtime.h>

// MPO config
#define DLEG 16
#define IN_SIZE 4096
#define OUT_SIZE 4096
#define BATCH 2048

typedef __attribute__((ext_vector_type(8))) __bf16 bf16x8;
typedef __attribute__((ext_vector_type(4))) float f32x4;

__device__ __forceinline__ unsigned short f2bf(float f) {
  unsigned u = __float_as_uint(f);
  u += 0x7fffu + ((u >> 16) & 1u);   // round-to-nearest-even
  return (unsigned short)(u >> 16);
}

__device__ __forceinline__ void async_copy16(const void* g, void* l) {
  __builtin_amdgcn_global_load_lds(
      (const __attribute__((address_space(1))) void*)g,
      (__attribute__((address_space(3))) void*)l, 16, 0, 0);
}

// ---------------------------------------------------------------------------
// Kernel 1: convert x (2048x4096 fp32) -> bf16, row-major.
// One float4 per thread. 8192 blocks x 256 threads.
// ---------------------------------------------------------------------------
__global__ __launch_bounds__(256) void k_cvt(const float* __restrict__ x,
                                             unsigned short* __restrict__ xb) {
  const int idx = blockIdx.x * 256 + threadIdx.x;
  const float4 v = ((const float4*)x)[idx];
  ushort4 o;
  o.x = f2bf(v.x); o.y = f2bf(v.y); o.z = f2bf(v.z); o.w = f2bf(v.w);
  ((ushort4*)xb)[idx] = o;
}

// ---------------------------------------------------------------------------
// Kernel 2: build Wt[n_col][k_row] (4096 x 4096 bf16), transposed W.
//   W[(i,j,k),(m,n,o)] = sum_{r,s} fc[i,r,m] * mc[j,r,s,n] * lc[k,s,o]
// One block per (i,j) (256 blocks, 256 threads).
// Phase A (LDS): A[m][n][s] = sum_r fc[i,r,m]*mc[j,r,s,n]   (4096 floats)
// Phase B: thread = (k = t&15, op = (t>>4)&3 -> 4 o's, mq = t>>6 -> 4 m's),
//          lc held in 64 registers, A read as float4 (contiguous in s).
// ---------------------------------------------------------------------------
__global__ __launch_bounds__(256) void k_build_wt(
    const float* __restrict__ fc, const float* __restrict__ mc,
    const float* __restrict__ lc, unsigned short* __restrict__ wt) {
  __shared__ float fc_s[256];    // [r][m]
  __shared__ float mc_s[4096];   // [r][s][n]
  __shared__ float a_s[4096];    // [m][n][s]
  const int b = blockIdx.x;      // b = i*16 + j
  const int i = b >> 4, j = b & 15;
  const int t = threadIdx.x;

  fc_s[t] = fc[i * 256 + t];
#pragma unroll
  for (int q = 0; q < 16; ++q) mc_s[q * 256 + t] = mc[j * 4096 + q * 256 + t];
  __syncthreads();

  {  // Phase A: thread handles (n = t>>4, s = t&15) for all m
    const int n = t >> 4, s = t & 15;
    float accm[16];
#pragma unroll
    for (int m = 0; m < 16; ++m) accm[m] = 0.f;
#pragma unroll
    for (int r = 0; r < 16; ++r) {
      const float mcv = mc_s[r * 256 + s * 16 + n];
#pragma unroll
      for (int m = 0; m < 16; ++m)
        accm[m] = fmaf(fc_s[r * 16 + m], mcv, accm[m]);
    }
#pragma unroll
    for (int m = 0; m < 16; ++m) a_s[m * 256 + n * 16 + s] = accm[m];
  }
  __syncthreads();

  // Phase B
  const int k = t & 15, op = (t >> 4) & 3, mq = t >> 6;
  float lcr[4][16];
#pragma unroll
  for (int oo = 0; oo < 4; ++oo)
#pragma unroll
    for (int s = 0; s < 16; ++s)
      lcr[oo][s] = lc[k * 256 + s * 16 + op * 4 + oo];

#pragma unroll
  for (int mm = 0; mm < 4; ++mm) {
    const int m = mq * 4 + mm;
#pragma unroll
    for (int n = 0; n < 16; ++n) {
      const float4* ap = (const float4*)&a_s[m * 256 + n * 16];
      float av[16];
      ((float4*)av)[0] = ap[0];
      ((float4*)av)[1] = ap[1];
      ((float4*)av)[2] = ap[2];
      ((float4*)av)[3] = ap[3];
      float accv[4] = {0.f, 0.f, 0.f, 0.f};
#pragma unroll
      for (int s = 0; s < 16; ++s) {
#pragma unroll
        for (int oo = 0; oo < 4; ++oo)
          accv[oo] = fmaf(av[s], lcr[oo][s], accv[oo]);
      }
      const size_t colbase = (size_t)(m * 256 + n * 16 + op * 4);
#pragma unroll
      for (int oo = 0; oo < 4; ++oo)
        wt[(colbase + oo) * 4096 + b * 16 + k] = f2bf(accv[oo]);
    }
  }
}

// ---------------------------------------------------------------------------
// Kernel 3: GEMM  out[2048,4096] = Xbf @ Wt^T + bias  (fp32 out)
// m97 recipe: BM=BN=128, BK=32, 256 threads (4 waves, 2x2), each wave 64x64
// via 4x4 frags of mfma_f32_16x16x32_bf16. global_load_lds width=16 staging.
// Wt is N x K row-major so B-fragments are contiguous ds_read_b128.
// Grid: (4096/128, 2048/128) = (32, 16)
// ---------------------------------------------------------------------------
__global__ __launch_bounds__(256) void k_gemm(
    const unsigned short* __restrict__ X,    // 2048 x 4096 (bf16 bits)
    const unsigned short* __restrict__ Wt,   // 4096(n) x 4096(k)
    const float* __restrict__ bias,
    float* __restrict__ out) {
  __shared__ unsigned short As[128 * 32];  // 8KB, row-major 128x32
  __shared__ unsigned short Bs[128 * 32];  // 8KB

  const int t = threadIdx.x;
  const int l = t & 63;
  const int w = t >> 6;
  const int wm = w >> 1, wn = w & 1;
  const int m0 = blockIdx.y * 128, n0 = blockIdx.x * 128;

  // staging: chunk c covers tile row c>>2, 8-col group c&3 (16B)
  const int c0 = t, c1 = t + 256;
  const unsigned short* xg0 = X + (size_t)(m0 + (c0 >> 2)) * 4096 + (c0 & 3) * 8;
  const unsigned short* xg1 = X + (size_t)(m0 + (c1 >> 2)) * 4096 + (c1 & 3) * 8;
  const unsigned short* wg0 = Wt + (size_t)(n0 + (c0 >> 2)) * 4096 + (c0 & 3) * 8;
  const unsigned short* wg1 = Wt + (size_t)(n0 + (c1 >> 2)) * 4096 + (c1 & 3) * 8;
  unsigned short* lA0 = As + c0 * 8;
  unsigned short* lA1 = As + c1 * 8;
  unsigned short* lB0 = Bs + c0 * 8;
  unsigned short* lB1 = Bs + c1 * 8;

  // fragment addressing: A[m=lane&15][k=(lane>>4)*8+j], B[n=lane&15][k=...]
  const int arow = wm * 64 + (l & 15);
  const int brow = wn * 64 + (l & 15);
  const int koff = (l >> 4) * 8;

  f32x4 acc[4][4];
#pragma unroll
  for (int a = 0; a < 4; ++a)
#pragma unroll
    for (int c = 0; c < 4; ++c) acc[a][c] = (f32x4){0.f, 0.f, 0.f, 0.f};

  for (int kt = 0; kt < 4096; kt += 32) {
    async_copy16(xg0 + kt, lA0);
    async_copy16(xg1 + kt, lA1);
    async_copy16(wg0 + kt, lB0);
    async_copy16(wg1 + kt, lB1);
    __syncthreads();  // drains vmcnt before barrier -> staging complete

    bf16x8 af[4], bfr[4];
#pragma unroll
    for (int mi = 0; mi < 4; ++mi)
      af[mi] = *(const bf16x8*)&As[(arow + mi * 16) * 32 + koff];
#pragma unroll
    for (int ni = 0; ni < 4; ++ni)
      bfr[ni] = *(const bf16x8*)&Bs[(brow + ni * 16) * 32 + koff];

#pragma unroll
    for (int mi = 0; mi < 4; ++mi)
#pragma unroll
      for (int ni = 0; ni < 4; ++ni)
        acc[mi][ni] = __builtin_amdgcn_mfma_f32_16x16x32_bf16(
            af[mi], bfr[ni], acc[mi][ni], 0, 0, 0);
    __syncthreads();  // protect LDS before next staging
  }

  // epilogue: C/D layout col = lane&15, row = (lane>>4)*4 + reg
#pragma unroll
  for (int ni = 0; ni < 4; ++ni) {
    const int col = n0 + wn * 64 + ni * 16 + (l & 15);
    const float bv = bias[col];
#pragma unroll
    for (int mi = 0; mi < 4; ++mi) {
      const int row = m0 + wm * 64 + mi * 16 + (l >> 4) * 4;
#pragma unroll
      for (int r = 0; r < 4; ++r)
        out[(size_t)(row + r) * 4096 + col] = acc[mi][ni][r] + bv;
    }
  }
}

// ---------------------------------------------------------------------------
extern "C" void kernel_launch(void* const* d_in, const int* in_sizes, int n_in,
                              void* d_out, int out_size, void* d_ws,
                              size_t ws_size, hipStream_t stream) {
  const float* x    = (const float*)d_in[0];
  const float* fc   = (const float*)d_in[1];
  const float* mc   = (const float*)d_in[2];
  const float* lc   = (const float*)d_in[3];
  const float* bias = (const float*)d_in[4];
  float* out = (float*)d_out;

  unsigned short* xb = (unsigned short*)d_ws;                       // 16.8 MB
  unsigned short* wt = xb + (size_t)BATCH * IN_SIZE;                // 33.6 MB

  k_cvt<<<(BATCH * IN_SIZE / 4) / 256, 256, 0, stream>>>(x, xb);
  k_build_wt<<<256, 256, 0, stream>>>(fc, mc, lc, wt);
  k_gemm<<<dim3(OUT_SIZE / 128, BATCH / 128), 256, 0, stream>>>(xb, wt, bias, out);
}